// Round 6
// baseline (295.531 us; speedup 1.0000x reference)
//
#include <hip/hip_runtime.h>

#define N_NODES 100000
#define N_EDGES 3200000
#define CH 256

#define EPB 2048         // edges per sort block
#define GS 1563          // ceil(N_EDGES/EPB); last block has 1024
#define NB2 25           // bucket = row >> 12
#define BSZ 4096         // node span per bucket
#define G_AGG 16         // slices per bucket
#define SLICE 98         // ceil(GS/G_AGG)
#define GRID_QK 1563     // 64 nodes/block
#define GRID_POOL 512

// ---- ws layout (float offsets) ----
#define OFF_TOTAL  0
#define OFF_PTOT   16        // 1563
#define OFF_YUP    1584      // 512*256 = 131072 (plain stores, no init needed)
#define OFF_PRE    132656    // 1563*26 = 40638 ints (pad 40640)
#define OFF_Q      173296    // 100000
#define OFF_K      273296    // 100000
#define OFF_PART   373296    // 25*16*4096 = 1638400
#define OFF_EX     2011696   // 1563*2048 = 3201024
#define OFF_ROW    5212720   // 3201024 u16 = 1600512 floats
// end = 6813232 floats = 27.25 MB <= 28.05 MB (known ws floor from R3)

// q[n]=x[n,:].Wq+bq, k[n]=x[n,:].Wk+bk. 16-lane dot groups.
__global__ __launch_bounds__(256) void k_qk(const float* __restrict__ x,
                                            const float* __restrict__ Wq,
                                            const float* __restrict__ bq,
                                            const float* __restrict__ Wk,
                                            const float* __restrict__ bk,
                                            float* __restrict__ q,
                                            float* __restrict__ k) {
    int t = threadIdx.x;
    int w = t >> 6, lane = t & 63;
    int g = lane >> 4, seg = lane & 15;
    float4 wq4[4], wk4[4];
    #pragma unroll
    for (int j = 0; j < 4; ++j) {
        wq4[j] = ((const float4*)Wq)[seg + 16 * j];
        wk4[j] = ((const float4*)Wk)[seg + 16 * j];
    }
    float bqs = bq[0], bks = bk[0];
    int base = blockIdx.x * 64 + w * 16 + g;
    #pragma unroll
    for (int i = 0; i < 4; ++i) {
        int n = base + i * 4;
        if (n < N_NODES) {
            const float4* xr = (const float4*)(x + (size_t)n * CH);
            float dq = 0.0f, dk = 0.0f;
            #pragma unroll
            for (int j = 0; j < 4; ++j) {
                float4 xv = xr[seg + 16 * j];
                dq = fmaf(xv.x, wq4[j].x, fmaf(xv.y, wq4[j].y,
                     fmaf(xv.z, wq4[j].z, fmaf(xv.w, wq4[j].w, dq))));
                dk = fmaf(xv.x, wk4[j].x, fmaf(xv.y, wk4[j].y,
                     fmaf(xv.z, wk4[j].z, fmaf(xv.w, wk4[j].w, dk))));
            }
            dq += __shfl_down(dq, 8); dq += __shfl_down(dq, 4);
            dq += __shfl_down(dq, 2); dq += __shfl_down(dq, 1);
            dk += __shfl_down(dk, 8); dk += __shfl_down(dk, 4);
            dk += __shfl_down(dk, 2); dk += __shfl_down(dk, 1);
            if (seg == 0) { q[n] = dq + bqs; k[n] = dk + bks; }
        }
    }
}

// 2048 edges/block, 256 thr: LDS counting sort by bucket + exp + per-block sum.
__global__ __launch_bounds__(256) void k_sort(const int* __restrict__ ei,
                                              const float* __restrict__ q,
                                              const float* __restrict__ k,
                                              float* __restrict__ ex_out,
                                              unsigned short* __restrict__ row_out,
                                              int* __restrict__ pre,
                                              float* __restrict__ ptot) {
    __shared__ int cnt[4][NB2];
    __shared__ int bsum[NB2];
    __shared__ int pref[NB2 + 1];
    __shared__ float lex[EPB];
    __shared__ unsigned short lrow[EPB];
    __shared__ float sm[4];
    int t = threadIdx.x, blk = blockIdx.x, w = t >> 6;
    int e0 = blk * EPB;
    int ecnt = min(EPB, N_EDGES - e0);
    if (t < 4 * NB2) ((int*)cnt)[t] = 0;
    __syncthreads();
    int rr[8]; float ee[8];
    #pragma unroll
    for (int j = 0; j < 8; ++j) {
        int i = j * 256 + t;
        if (i < ecnt) {
            int r = ei[e0 + i], c = ei[N_EDGES + e0 + i];
            float v = q[r] * k[c];
            v = (v >= 0.0f) ? v : 0.2f * v;
            rr[j] = r; ee[j] = __expf(v);
            atomicAdd(&cnt[w][r >> 12], 1);
        } else { rr[j] = -1; ee[j] = 0.0f; }
    }
    __syncthreads();
    if (t < NB2) {   // convert per-wave counts to per-wave exclusive bases
        int c0 = cnt[0][t], c1 = cnt[1][t], c2 = cnt[2][t], c3 = cnt[3][t];
        cnt[0][t] = 0; cnt[1][t] = c0; cnt[2][t] = c0 + c1; cnt[3][t] = c0 + c1 + c2;
        bsum[t] = c0 + c1 + c2 + c3;
    }
    __syncthreads();
    if (t == 0) {
        int run = 0;
        #pragma unroll
        for (int b = 0; b < NB2; ++b) { pref[b] = run; run += bsum[b]; }
        pref[NB2] = run;
    }
    __syncthreads();
    if (t < 4 * NB2) { int ww = t / NB2, b = t - ww * NB2; cnt[ww][b] += pref[b]; }
    if (t < NB2 + 1) pre[blk * 26 + t] = pref[t];
    __syncthreads();
    #pragma unroll
    for (int j = 0; j < 8; ++j) {
        if (rr[j] >= 0) {
            int b = rr[j] >> 12;
            int p = atomicAdd(&cnt[w][b], 1);  // rank + slot in one atomic
            lex[p] = ee[j];
            lrow[p] = (unsigned short)(rr[j] & (BSZ - 1));
        }
    }
    float s = ((ee[0] + ee[1]) + (ee[2] + ee[3])) + ((ee[4] + ee[5]) + (ee[6] + ee[7]));
    #pragma unroll
    for (int off = 32; off; off >>= 1) s += __shfl_down(s, off);
    if ((t & 63) == 0) sm[w] = s;
    __syncthreads();  // placement + sm complete
    if (t == 0) ptot[blk] = sm[0] + sm[1] + sm[2] + sm[3];
    size_t gb = (size_t)blk * EPB;
    for (int i = t; i < ecnt; i += 256) ex_out[gb + i] = lex[i];
    unsigned* ro = (unsigned*)(row_out + gb);
    const unsigned* lr = (const unsigned*)lrow;
    int words = (ecnt + 1) >> 1;
    for (int i = t; i < words; i += 256) ro[i] = lr[i];
}

// (bucket b, slice g): per-wave segment runs into LDS acc[4096] -> dense partial.
__global__ __launch_bounds__(256) void k_agg(const float* __restrict__ ex,
                                             const unsigned short* __restrict__ row,
                                             const int* __restrict__ pre,
                                             float* __restrict__ partial) {
    int b = blockIdx.x / G_AGG, g = blockIdx.x % G_AGG;
    __shared__ float acc[BSZ];
    int t = threadIdx.x, w = t >> 6, lane = t & 63;
    for (int i = t; i < BSZ; i += 256) acc[i] = 0.0f;
    __syncthreads();
    int sb0 = g * SLICE, sb1 = min(sb0 + SLICE, GS);
    for (int sb = sb0 + w; sb < sb1; sb += 4) {
        size_t gbase = (size_t)sb * EPB;
        int s0 = pre[sb * 26 + b], s1 = pre[sb * 26 + b + 1];
        for (int i = s0 + lane; i < s1; i += 64)
            atomicAdd(&acc[row[gbase + i]], ex[gbase + i]);
    }
    __syncthreads();
    float* dst = partial + ((size_t)b * G_AGG + g) * BSZ;
    for (int i = t; i < BSZ; i += 256) dst[i] = acc[i];
}

// total from ptot; awu on-the-fly from partial slices; x-weighted pool; aw_out.
__global__ __launch_bounds__(256) void k_pool(const float* __restrict__ x,
                                              const float* __restrict__ partial,
                                              const float* __restrict__ ptot,
                                              float* __restrict__ totalp,
                                              float* __restrict__ yup,
                                              float* __restrict__ aw_out) {
    int t = threadIdx.x, s = t >> 6, g = t & 63;
    float ts = 0.0f;
    for (int i = t; i < GS; i += 256) ts += ptot[i];
    #pragma unroll
    for (int off = 32; off; off >>= 1) ts += __shfl_down(ts, off);
    __shared__ float sm[4];
    __shared__ float totsh;
    if (g == 0) sm[s] = ts;
    __syncthreads();
    if (t == 0) {
        totsh = sm[0] + sm[1] + sm[2] + sm[3];
        if (blockIdx.x == 0) totalp[0] = totsh;
    }
    __syncthreads();
    float inv = 1.0f / totsh;

    __shared__ float awA[2][8], awB[2][8];
    const float4* X4 = (const float4*)x;
    float4 acc = make_float4(0.f, 0.f, 0.f, 0.f);
    int p = 0;
    for (int base = blockIdx.x * 8; base < N_NODES; base += GRID_POOL * 8, p ^= 1) {
        int bkt = base >> 12, off = base & (BSZ - 1);
        float pv = 0.0f;
        if (t < 128) {  // slice sl = t>>3 (0..15), node off no = t&7: 32B runs
            int sl = t >> 3, no = t & 7;
            pv = partial[((size_t)bkt * G_AGG + sl) * BSZ + off + no];
        }
        // stride-8 reduce within each wave: wave0 sums slices 0-7, wave1 slices 8-15
        pv += __shfl_down(pv, 32);
        pv += __shfl_down(pv, 16);
        pv += __shfl_down(pv, 8);
        if (t < 8) awA[p][t] = pv;
        else if (t >= 64 && t < 72) awB[p][t - 64] = pv;
        __syncthreads();
        float a0 = awA[p][s] + awB[p][s];
        float a1 = awA[p][4 + s] + awB[p][4 + s];
        if (t < 8) aw_out[base + t] = (awA[p][t] + awB[p][t]) * inv;
        float4 x0 = X4[(size_t)(base + s) * 64 + g];
        float4 x1 = X4[(size_t)(base + 4 + s) * 64 + g];
        acc.x = fmaf(a0, x0.x, acc.x); acc.y = fmaf(a0, x0.y, acc.y);
        acc.z = fmaf(a0, x0.z, acc.z); acc.w = fmaf(a0, x0.w, acc.w);
        acc.x = fmaf(a1, x1.x, acc.x); acc.y = fmaf(a1, x1.y, acc.y);
        acc.z = fmaf(a1, x1.z, acc.z); acc.w = fmaf(a1, x1.w, acc.w);
    }
    __syncthreads();
    __shared__ float4 tmp4[4][64];
    tmp4[s][g] = acc;
    __syncthreads();
    const float* tmp = (const float*)tmp4;
    float sum = tmp[0 * 256 + t] + tmp[1 * 256 + t] + tmp[2 * 256 + t] + tmp[3 * 256 + t];
    yup[(size_t)blockIdx.x * 256 + t] = sum;
}

// grid 8: fold yup rows -> y; block j computes out[j*32 .. j*32+32)
__global__ __launch_bounds__(256) void k_final(const float* __restrict__ yup,
                                               const float* __restrict__ totalp,
                                               const float* __restrict__ Wv,
                                               const float* __restrict__ bv,
                                               float* __restrict__ out) {
    __shared__ float ysh[256];
    __shared__ float red[256];
    int t = threadIdx.x;
    float inv = 1.0f / totalp[0];
    float yv = 0.0f;
    #pragma unroll 8
    for (int r = 0; r < GRID_POOL; ++r) yv += yup[(size_t)r * 256 + t];
    ysh[t] = yv * inv;
    __syncthreads();
    int c = blockIdx.x * 32 + (t & 31), rg = t >> 5;
    float acc = 0.0f;
    #pragma unroll
    for (int j = 0; j < 32; ++j) {
        int kk = rg * 32 + j;
        acc = fmaf(ysh[kk], Wv[(size_t)kk * CH + c], acc);
    }
    red[t] = acc;
    __syncthreads();
    if (t < 32) {
        float sv = 0.0f;
        #pragma unroll
        for (int j = 0; j < 8; ++j) sv += red[j * 32 + t];
        out[blockIdx.x * 32 + t] = sv + bv[blockIdx.x * 32 + t];
    }
}

extern "C" void kernel_launch(void* const* d_in, const int* in_sizes, int n_in,
                              void* d_out, int out_size, void* d_ws, size_t ws_size,
                              hipStream_t stream) {
    const float* x  = (const float*)d_in[0];
    const int*   ei = (const int*)d_in[1];
    const float* Wq = (const float*)d_in[2];
    const float* bq = (const float*)d_in[3];
    const float* Wk = (const float*)d_in[4];
    const float* bk = (const float*)d_in[5];
    const float* Wv = (const float*)d_in[6];
    const float* bv = (const float*)d_in[7];
    float* out = (float*)d_out;
    float* ws  = (float*)d_ws;

    float*          totalp  = ws + OFF_TOTAL;
    float*          ptot    = ws + OFF_PTOT;
    float*          yup     = ws + OFF_YUP;
    int*            pre     = (int*)(ws + OFF_PRE);
    float*          q       = ws + OFF_Q;
    float*          k       = ws + OFF_K;
    float*          partial = ws + OFF_PART;
    float*          ex      = ws + OFF_EX;
    unsigned short* row     = (unsigned short*)(ws + OFF_ROW);

    hipLaunchKernelGGL(k_qk, dim3(GRID_QK), dim3(256), 0, stream,
                       x, Wq, bq, Wk, bk, q, k);
    hipLaunchKernelGGL(k_sort, dim3(GS), dim3(256), 0, stream,
                       ei, q, k, ex, row, pre, ptot);
    hipLaunchKernelGGL(k_agg, dim3(NB2 * G_AGG), dim3(256), 0, stream,
                       ex, row, pre, partial);
    hipLaunchKernelGGL(k_pool, dim3(GRID_POOL), dim3(256), 0, stream,
                       x, partial, ptot, totalp, yup, out + CH);
    hipLaunchKernelGGL(k_final, dim3(8), dim3(256), 0, stream,
                       yup, totalp, Wv, bv, out);
}